// Round 8
// baseline (292.053 us; speedup 1.0000x reference)
//
#include <hip/hip_runtime.h>

// Per-node MLP 16->256->128->6->128->256->1 (tanh...sigmoid) on
// edge_attr.reshape(500000,16). x / edge_index are dead inputs.
//
// R8: merge k1+k2 into ONE 1024-thread kernel (both weight sets resident:
// LDS 156.7KB = 1 block/CU x 16 waves = same 4 waves/SIMD as the R7 split,
// but z never leaves registers, one launch + one staging pass saved, LDS
// mirrors g_img exactly). MFMA accumulator chains split in two (ki-halves)
// in L2/L3/L5 for 2x independent chains per fence window (stall reduction).
// Weight folding (R7): tanh(x)=2*sigma(2x)-1 baked into weights; activation
// is s = rcp(1+exp2(y)). In-lane C->B via permuted-k weights (R6): no
// cross-lane ops between layers. Fence windows bound scheduler hoisting (R5).

#define N_NODES 500000

// ---- weight-image layout in g_img == LDS layout (bytes) ----
#define OFF_W1 0        // 16 x 512B  (L1: K=16, standard k-order, x -2log2e)
#define OFF_W2 8192     // 64 x 1KB   (L2, permuted k, x -4log2e)
#define OFF_W3 73728    // 4  x 1KB   (L3, permuted k, x -4log2e)
#define OFF_W4 77824    // 8  x 1KB   (L4: z C-layout feed, x -4log2e)
#define OFF_W5 86016    // 64 x 1KB   (L5, permuted k, x -4log2e)
#define OFF_WO 151552   // 256 f32 (2*Wo)
#define OFF_B1 152576   // 256 f32 (S*b1)
#define OFF_B2 153600   // 128 f32 (S*(be1 - colsum We1))
#define OFF_B3 154112   // 16 f32  (S*(be2 - colsum We2), 6 valid)
#define OFF_B4 154176   // 128 f32 (S*(bd1 - colsum Wd1))
#define OFF_B5 154688   // 256 f32 (S*(bd2 - colsum Wd2))
#define OFF_EXTRA 155712 // 16B: [0] = bo - Sum Wo
#define OFF_ZERO  155728 // 512B zeros (L1 K-pad A rows)
#define IMG_END   156240
#define IMG_ALLOC 156672   // staging tail pad (group 152 lanes 37..63)
#define ALL_LDS   156672   // <= 163840: 1 block/CU

#define SCONST (-2.8853900817779268f)   // -2*log2(e)

typedef _Float16 half8  __attribute__((ext_vector_type(8)));
typedef __fp16   pk16x2 __attribute__((ext_vector_type(2)));
typedef float    f32x4  __attribute__((ext_vector_type(4)));
typedef int      int4v  __attribute__((ext_vector_type(4)));

__device__ __align__(16) char g_img[IMG_ALLOC];

static __device__ __forceinline__ unsigned pack_f16_rne(float a, float b) {
  _Float16 ha = (_Float16)a, hb = (_Float16)b;
  unsigned short ua = __builtin_bit_cast(unsigned short, ha);
  unsigned short ub = __builtin_bit_cast(unsigned short, hb);
  return (unsigned)ua | ((unsigned)ub << 16);
}
static __device__ __forceinline__ int pkrtz(float a, float b) {
  pk16x2 h = __builtin_amdgcn_cvt_pkrtz(a, b);
  return __builtin_bit_cast(int, h);
}
// s = 1/(1+2^y); with y = -2*log2e*(Wx+b) this is sigma(2*(Wx+b)).
static __device__ __forceinline__ float sig2(float y) {
  float e = __builtin_amdgcn_exp2f(y);
  return __builtin_amdgcn_rcpf(1.0f + e);
}
static __device__ __forceinline__ float sigmoid_f(float x) {
  float e = __builtin_amdgcn_exp2f(x * -1.4426950408889634f);
  return __builtin_amdgcn_rcpf(1.0f + e);
}
static __device__ __forceinline__ f32x4 mfma16(half8 a, int4v b, f32x4 c) {
  return __builtin_amdgcn_mfma_f32_16x16x32_f16(a, __builtin_bit_cast(half8, b), c, 0, 0, 0);
}
static __device__ __forceinline__ half8 lda(const char* smem, int off) {
  return *(const half8*)(smem + off);
}
static __device__ __forceinline__ f32x4 ldf4(const char* smem, int off) {
  return *(const f32x4*)(smem + off);
}
#define FENCE() __builtin_amdgcn_sched_barrier(0)

struct PK2 { int lo, hi; };
static __device__ __forceinline__ PK2 tp(f32x4 a) {
  PK2 p;
  p.lo = pkrtz(sig2(a.x), sig2(a.y));
  p.hi = pkrtz(sig2(a.z), sig2(a.w));
  return p;
}

// ---------------- prep (unchanged from R7) ----------------
__global__ void gnn_prep(const float* __restrict__ W1,  const float* __restrict__ b1,
                         const float* __restrict__ We1, const float* __restrict__ be1,
                         const float* __restrict__ We2, const float* __restrict__ be2,
                         const float* __restrict__ Wd1, const float* __restrict__ bd1,
                         const float* __restrict__ Wd2, const float* __restrict__ bd2,
                         const float* __restrict__ Wo,  const float* __restrict__ bo)
{
  int t = blockIdx.x * 256 + threadIdx.x;
  int off = t * 4;
  if (off >= IMG_END) return;
  unsigned val;
  if (off < OFF_W2) {                     // L1 (K=16): standard order, S*W1
    int rel = off;
    int mi = rel >> 9, li = (rel >> 4) & 31, j2 = (rel >> 2) & 3;
    int fout = mi * 16 + (li & 15);
    int k0 = (li >> 4) * 8 + j2 * 2;
    val = pack_f16_rne(SCONST * W1[k0 * 256 + fout], SCONST * W1[(k0 + 1) * 256 + fout]);
  } else if (off < OFF_W3) {              // L2: permuted k, 2S*We1
    int rel = off - OFF_W2;
    int blk = rel >> 10, li = (rel >> 4) & 63, j2 = (rel >> 2) & 3;
    int mi = blk >> 3, ki = blk & 7;
    int fout = mi * 16 + (li & 15);
    int k0 = ki * 32 + 4 * (li >> 4) + 16 * (j2 >> 1) + 2 * (j2 & 1);
    val = pack_f16_rne(2.0f * SCONST * We1[k0 * 128 + fout],
                       2.0f * SCONST * We1[(k0 + 1) * 128 + fout]);
  } else if (off < OFF_W4) {              // L3: permuted k, 2S*We2 (fout pad 16)
    int rel = off - OFF_W3;
    int ki = rel >> 10, li = (rel >> 4) & 63, j2 = (rel >> 2) & 3;
    int fo = li & 15;
    int k0 = ki * 32 + 4 * (li >> 4) + 16 * (j2 >> 1) + 2 * (j2 & 1);
    float a = (fo < 6) ? 2.0f * SCONST * We2[k0 * 6 + fo] : 0.0f;
    float b = (fo < 6) ? 2.0f * SCONST * We2[(k0 + 1) * 6 + fo] : 0.0f;
    val = pack_f16_rne(a, b);
  } else if (off < OFF_W5) {              // L4: z C-layout feed, 2S*Wd1
    int rel = off - OFF_W4;
    int mi = rel >> 10, li = (rel >> 4) & 63, j2 = (rel >> 2) & 3;
    int fout = mi * 16 + (li & 15);
    int qa = li >> 4;
    unsigned v = 0;
    if (j2 < 2) {
      int k0 = 4 * qa + 2 * j2;
      float a = (k0 < 6)     ? 2.0f * SCONST * Wd1[k0 * 128 + fout]       : 0.0f;
      float b = (k0 + 1 < 6) ? 2.0f * SCONST * Wd1[(k0 + 1) * 128 + fout] : 0.0f;
      v = pack_f16_rne(a, b);
    }
    val = v;
  } else if (off < OFF_WO) {              // L5: permuted k, 2S*Wd2
    int rel = off - OFF_W5;
    int blk = rel >> 10, li = (rel >> 4) & 63, j2 = (rel >> 2) & 3;
    int mi = blk >> 2, ki = blk & 3;
    int fout = mi * 16 + (li & 15);
    int k0 = ki * 32 + 4 * (li >> 4) + 16 * (j2 >> 1) + 2 * (j2 & 1);
    val = pack_f16_rne(2.0f * SCONST * Wd2[k0 * 256 + fout],
                       2.0f * SCONST * Wd2[(k0 + 1) * 256 + fout]);
  } else if (off < OFF_B1) {              // wo' = 2*Wo
    val = __builtin_bit_cast(unsigned, 2.0f * Wo[(off - OFF_WO) >> 2]);
  } else if (off < OFF_B2) {              // S*b1
    val = __builtin_bit_cast(unsigned, SCONST * b1[(off - OFF_B1) >> 2]);
  } else if (off < OFF_B3) {              // S*(be1 - colsum We1)
    int i = (off - OFF_B2) >> 2;
    float s = 0.0f;
    for (int k = 0; k < 256; ++k) s += We1[k * 128 + i];
    val = __builtin_bit_cast(unsigned, SCONST * (be1[i] - s));
  } else if (off < OFF_B4) {              // S*(be2 - colsum We2), pad 0
    int i = (off - OFF_B3) >> 2;
    float v = 0.0f;
    if (i < 6) {
      float s = 0.0f;
      for (int k = 0; k < 128; ++k) s += We2[k * 6 + i];
      v = SCONST * (be2[i] - s);
    }
    val = __builtin_bit_cast(unsigned, v);
  } else if (off < OFF_B5) {              // S*(bd1 - colsum Wd1)
    int i = (off - OFF_B4) >> 2;
    float s = 0.0f;
    for (int k = 0; k < 6; ++k) s += Wd1[k * 128 + i];
    val = __builtin_bit_cast(unsigned, SCONST * (bd1[i] - s));
  } else if (off < OFF_EXTRA) {           // S*(bd2 - colsum Wd2)
    int i = (off - OFF_B5) >> 2;
    float s = 0.0f;
    for (int k = 0; k < 128; ++k) s += Wd2[k * 256 + i];
    val = __builtin_bit_cast(unsigned, SCONST * (bd2[i] - s));
  } else if (off == OFF_EXTRA) {          // bo' = bo - Sum Wo
    float s = 0.0f;
    for (int k = 0; k < 256; ++k) s += Wo[k];
    val = __builtin_bit_cast(unsigned, bo[0] - s);
  } else {                                // extra slot tail + zero block
    val = 0;
  }
  *(unsigned*)(g_img + off) = val;
}

static __device__ __forceinline__ void stage_chunk(const char* src, char* dst) {
  __builtin_amdgcn_global_load_lds(
      (const __attribute__((address_space(1))) void*)src,
      (__attribute__((address_space(3))) void*)dst, 16, 0, 0);
}

// ================= merged kernel: L1..L5 + output =================

#define L1_PAIR(KO, OUT_G0, OUT_G1) do {                                   \
    half8 Ae = lda(smem, w1b + (2*(KO))*w1s);                              \
    half8 Ao = lda(smem, w1b + (2*(KO)+1)*w1s);                            \
    f32x4 be_ = ldf4(smem, OFF_B1 + (2*(KO))*64 + q*16);                   \
    f32x4 bo_ = ldf4(smem, OFF_B1 + (2*(KO)+1)*64 + q*16);                 \
    f32x4 ae0 = mfma16(Ae, b1g0, be_);                                     \
    f32x4 ae1 = mfma16(Ae, b1g1, be_);                                     \
    f32x4 ao0 = mfma16(Ao, b1g0, bo_);                                     \
    f32x4 ao1 = mfma16(Ao, b1g1, bo_);                                     \
    PK2 pe0 = tp(ae0), po0 = tp(ao0), pe1 = tp(ae1), po1 = tp(ao1);        \
    OUT_G0.x = pe0.lo; OUT_G0.y = pe0.hi; OUT_G0.z = po0.lo; OUT_G0.w = po0.hi; \
    OUT_G1.x = pe1.lo; OUT_G1.y = pe1.hi; OUT_G1.z = po1.lo; OUT_G1.w = po1.hi; \
    FENCE();                                                               \
  } while (0)

// Split accumulator chains: ki 0..3 on the bias-chain, ki 4..7 on a zero
// chain, summed at the end — 2x independent MFMA chains per output.
#define L2_MI(MI, ACC0, ACC1) do {                                                            \
    f32x4 bb = ldf4(smem, OFF_B2 + (MI)*64 + q*16);                                           \
    f32x4 x0a = bb, x0b = zf4, x1a = bb, x1b = zf4;                                           \
    half8 A;                                                                                  \
    A = lda(smem, OFF_W2 + ((MI)*8+0)*1024 + ln*16); x0a = mfma16(A, c2g0_0, x0a); x1a = mfma16(A, c2g1_0, x1a); \
    A = lda(smem, OFF_W2 + ((MI)*8+4)*1024 + ln*16); x0b = mfma16(A, c2g0_4, x0b); x1b = mfma16(A, c2g1_4, x1b); \
    A = lda(smem, OFF_W2 + ((MI)*8+1)*1024 + ln*16); x0a = mfma16(A, c2g0_1, x0a); x1a = mfma16(A, c2g1_1, x1a); \
    A = lda(smem, OFF_W2 + ((MI)*8+5)*1024 + ln*16); x0b = mfma16(A, c2g0_5, x0b); x1b = mfma16(A, c2g1_5, x1b); \
    A = lda(smem, OFF_W2 + ((MI)*8+2)*1024 + ln*16); x0a = mfma16(A, c2g0_2, x0a); x1a = mfma16(A, c2g1_2, x1a); \
    A = lda(smem, OFF_W2 + ((MI)*8+6)*1024 + ln*16); x0b = mfma16(A, c2g0_6, x0b); x1b = mfma16(A, c2g1_6, x1b); \
    A = lda(smem, OFF_W2 + ((MI)*8+3)*1024 + ln*16); x0a = mfma16(A, c2g0_3, x0a); x1a = mfma16(A, c2g1_3, x1a); \
    A = lda(smem, OFF_W2 + ((MI)*8+7)*1024 + ln*16); x0b = mfma16(A, c2g0_7, x0b); x1b = mfma16(A, c2g1_7, x1b); \
    ACC0 = x0a + x0b; ACC1 = x1a + x1b;                                                       \
  } while (0)

#define L2_PAIR(KO, OUT_G0, OUT_G1) do {                                   \
    f32x4 ve0, ve1, vo0, vo1;                                              \
    L2_MI(2*(KO),   ve0, ve1);                                             \
    FENCE();                                                               \
    L2_MI(2*(KO)+1, vo0, vo1);                                             \
    PK2 pe0 = tp(ve0), po0 = tp(vo0), pe1 = tp(ve1), po1 = tp(vo1);        \
    OUT_G0.x = pe0.lo; OUT_G0.y = pe0.hi; OUT_G0.z = po0.lo; OUT_G0.w = po0.hi; \
    OUT_G1.x = pe1.lo; OUT_G1.y = pe1.hi; OUT_G1.z = po1.lo; OUT_G1.w = po1.hi; \
    FENCE();                                                               \
  } while (0)

#define L4_MI(MI, ACC0, ACC1) do {                                         \
    f32x4 bb = ldf4(smem, OFF_B4 + (MI)*64 + q*16);                        \
    half8 A = lda(smem, OFF_W4 + (MI)*1024 + ln*16);                       \
    ACC0 = mfma16(A, b4g0, bb);                                            \
    ACC1 = mfma16(A, b4g1, bb);                                            \
  } while (0)

#define L4_PAIR(KO, OUT_G0, OUT_G1) do {                                   \
    f32x4 ve0, ve1, vo0, vo1;                                              \
    L4_MI(2*(KO),   ve0, ve1);                                             \
    L4_MI(2*(KO)+1, vo0, vo1);                                             \
    PK2 pe0 = tp(ve0), po0 = tp(vo0), pe1 = tp(ve1), po1 = tp(vo1);        \
    OUT_G0.x = pe0.lo; OUT_G0.y = pe0.hi; OUT_G0.z = po0.lo; OUT_G0.w = po0.hi; \
    OUT_G1.x = pe1.lo; OUT_G1.y = pe1.hi; OUT_G1.z = po1.lo; OUT_G1.w = po1.hi; \
    FENCE();                                                               \
  } while (0)

#define L5_MI(MI) do {                                                                        \
    f32x4 bb = ldf4(smem, OFF_B5 + (MI)*64 + q*16);                                           \
    f32x4 x0a = bb, x0b = zf4, x1a = bb, x1b = zf4;                                           \
    half8 A;                                                                                  \
    A = lda(smem, OFF_W5 + ((MI)*4+0)*1024 + ln*16); x0a = mfma16(A, c5g0_0, x0a); x1a = mfma16(A, c5g1_0, x1a); \
    A = lda(smem, OFF_W5 + ((MI)*4+2)*1024 + ln*16); x0b = mfma16(A, c5g0_2, x0b); x1b = mfma16(A, c5g1_2, x1b); \
    A = lda(smem, OFF_W5 + ((MI)*4+1)*1024 + ln*16); x0a = mfma16(A, c5g0_1, x0a); x1a = mfma16(A, c5g1_1, x1a); \
    A = lda(smem, OFF_W5 + ((MI)*4+3)*1024 + ln*16); x0b = mfma16(A, c5g0_3, x0b); x1b = mfma16(A, c5g1_3, x1b); \
    f32x4 a0 = x0a + x0b, a1 = x1a + x1b;                                                     \
    f32x4 wo = ldf4(smem, OFF_WO + (MI)*64 + q*16);                                           \
    part0 += sig2(a0.x)*wo.x + sig2(a0.y)*wo.y + sig2(a0.z)*wo.z + sig2(a0.w)*wo.w;           \
    part1 += sig2(a1.x)*wo.x + sig2(a1.y)*wo.y + sig2(a1.z)*wo.z + sig2(a1.w)*wo.w;           \
    FENCE();                                                                                  \
  } while (0)

__global__ __launch_bounds__(1024, 4)
void gnn_all(const float* __restrict__ ea, float* __restrict__ out)
{
  __shared__ __align__(16) char smem[ALL_LDS];
  const int tid = threadIdx.x;
  const int wv = tid >> 6, ln = tid & 63;   // 16 waves

  // ---- stage whole weight image (LDS mirrors g_img) ----
  // 9765 16B-chunks -> 153 wave-groups of 64; tail group pads into IMG_ALLOC.
#pragma unroll 1
  for (int r = 0; r < 10; ++r) {
    int cb = r * 16 + wv;
    if (cb < 153)
      stage_chunk(g_img + (size_t)cb * 1024 + ln * 16,
                  smem + (size_t)cb * 1024 + ln * 16);
  }
  __syncthreads();

  const int q = ln >> 4, c = ln & 15;
  const bool qlo = (q < 2);
  const int lnl16 = (ln & 31) * 16;
  const int w1b = qlo ? (OFF_W1 + lnl16) : (OFF_ZERO + lnl16);
  const int w1s = qlo ? 512 : 0;
  const float bo2 = *(const float*)(smem + OFF_EXTRA);   // bo - Sum Wo
  const f32x4 zf4 = {0.0f, 0.0f, 0.0f, 0.0f};

  const int NT = (N_NODES + 511) / 512;   // 977 tiles of 512 nodes (16 waves)
#pragma unroll 1
  for (int t = blockIdx.x; t < NT; t += gridDim.x) {
    const int base = t * 512 + wv * 32;

    // ---- L1 input: edge_attr as X^T ----
    int nl = base + (q >> 1) * 16 + c;
    if (nl > N_NODES - 1) nl = N_NODES - 1;
    const f32x4* ea4 = (const f32x4*)ea;
    size_t eb = (size_t)nl * 4 + (size_t)((q & 1) * 2);
    f32x4 vlo = ea4[eb];
    f32x4 vhi = ea4[eb + 1];
    int4v b1g0;
    b1g0.x = pkrtz(vlo.x, vlo.y); b1g0.y = pkrtz(vlo.z, vlo.w);
    b1g0.z = pkrtz(vhi.x, vhi.y); b1g0.w = pkrtz(vhi.z, vhi.w);
    int sh = (ln + 32) & 63;
    int4v b1g1;
    b1g1.x = __shfl(b1g0.x, sh, 64); b1g1.y = __shfl(b1g0.y, sh, 64);
    b1g1.z = __shfl(b1g0.z, sh, 64); b1g1.w = __shfl(b1g0.w, sh, 64);

    // ---- L1: 16 -> 256 -> L2 B-frags ----
    int4v c2g0_0, c2g0_1, c2g0_2, c2g0_3, c2g0_4, c2g0_5, c2g0_6, c2g0_7;
    int4v c2g1_0, c2g1_1, c2g1_2, c2g1_3, c2g1_4, c2g1_5, c2g1_6, c2g1_7;
    L1_PAIR(0, c2g0_0, c2g1_0);
    L1_PAIR(1, c2g0_1, c2g1_1);
    L1_PAIR(2, c2g0_2, c2g1_2);
    L1_PAIR(3, c2g0_3, c2g1_3);
    L1_PAIR(4, c2g0_4, c2g1_4);
    L1_PAIR(5, c2g0_5, c2g1_5);
    L1_PAIR(6, c2g0_6, c2g1_6);
    L1_PAIR(7, c2g0_7, c2g1_7);

    // ---- L2: 256 -> 128 -> L3 B-frags ----
    int4v c3g0_0, c3g0_1, c3g0_2, c3g0_3;
    int4v c3g1_0, c3g1_1, c3g1_2, c3g1_3;
    L2_PAIR(0, c3g0_0, c3g1_0);
    L2_PAIR(1, c3g0_1, c3g1_1);
    L2_PAIR(2, c3g0_2, c3g1_2);
    L2_PAIR(3, c3g0_3, c3g1_3);

    // ---- L3: 128 -> 6 (split chains 2+2) ----
    f32x4 bb3 = ldf4(smem, OFF_B3 + q * 16);
    f32x4 z0a = bb3, z0b = zf4, z1a = bb3, z1b = zf4;
    {
      half8 A;
      A = lda(smem, OFF_W3 + 0 * 1024 + ln * 16); z0a = mfma16(A, c3g0_0, z0a); z1a = mfma16(A, c3g1_0, z1a);
      A = lda(smem, OFF_W3 + 2 * 1024 + ln * 16); z0b = mfma16(A, c3g0_2, z0b); z1b = mfma16(A, c3g1_2, z1b);
      A = lda(smem, OFF_W3 + 1 * 1024 + ln * 16); z0a = mfma16(A, c3g0_1, z0a); z1a = mfma16(A, c3g1_1, z1a);
      A = lda(smem, OFF_W3 + 3 * 1024 + ln * 16); z0b = mfma16(A, c3g0_3, z0b); z1b = mfma16(A, c3g1_3, z1b);
    }
    PK2 p3g0 = tp(z0a + z0b);
    PK2 p3g1 = tp(z1a + z1b);
    FENCE();

    // ---- L4 B-frags: direct in-register feed (zero W4 rows kill the
    //      sigma(0)=0.5 padding rows for q>=2 lanes; regs 2,3 are K-pad) ----
    int4v b4g0, b4g1;
    b4g0.x = p3g0.lo; b4g0.y = p3g0.hi; b4g0.z = 0; b4g0.w = 0;
    b4g1.x = p3g1.lo; b4g1.y = p3g1.hi; b4g1.z = 0; b4g1.w = 0;

    // ---- L4: 6 -> 128 -> L5 B-frags ----
    int4v c5g0_0, c5g0_1, c5g0_2, c5g0_3;
    int4v c5g1_0, c5g1_1, c5g1_2, c5g1_3;
    L4_PAIR(0, c5g0_0, c5g1_0);
    L4_PAIR(1, c5g0_1, c5g1_1);
    L4_PAIR(2, c5g0_2, c5g1_2);
    L4_PAIR(3, c5g0_3, c5g1_3);

    // ---- L5 + output: out = sigma(Sum wo'*s5 + bo') ----
    float part0 = 0.0f, part1 = 0.0f;
    L5_MI(0);  L5_MI(1);  L5_MI(2);  L5_MI(3);
    L5_MI(4);  L5_MI(5);  L5_MI(6);  L5_MI(7);
    L5_MI(8);  L5_MI(9);  L5_MI(10); L5_MI(11);
    L5_MI(12); L5_MI(13); L5_MI(14); L5_MI(15);

    part0 += __shfl_xor(part0, 16, 64); part0 += __shfl_xor(part0, 32, 64);
    part1 += __shfl_xor(part1, 16, 64); part1 += __shfl_xor(part1, 32, 64);
    if (q < 2) {
      int node = base + q * 16 + c;
      if (node < N_NODES) {
        float v = ((q == 0) ? part0 : part1) + bo2;
        out[node] = sigmoid_f(v);
      }
    }
  }
}

extern "C" void kernel_launch(void* const* d_in, const int* in_sizes, int n_in,
                              void* d_out, int out_size, void* d_ws, size_t ws_size,
                              hipStream_t stream) {
  (void)in_sizes; (void)n_in; (void)d_ws; (void)ws_size; (void)out_size;
  const float* ea  = (const float*)d_in[2];
  const float* W1  = (const float*)d_in[3];
  const float* b1  = (const float*)d_in[4];
  const float* We1 = (const float*)d_in[5];
  const float* be1 = (const float*)d_in[6];
  const float* We2 = (const float*)d_in[7];
  const float* be2 = (const float*)d_in[8];
  const float* Wd1 = (const float*)d_in[9];
  const float* bd1 = (const float*)d_in[10];
  const float* Wd2 = (const float*)d_in[11];
  const float* bd2 = (const float*)d_in[12];
  const float* Wo  = (const float*)d_in[13];
  const float* bo  = (const float*)d_in[14];

  gnn_prep<<<dim3((IMG_END / 4 + 255) / 256), dim3(256), 0, stream>>>(
      W1, b1, We1, be1, We2, be2, Wd1, bd1, Wd2, bd2, Wo, bo);
  gnn_all<<<dim3(256), dim3(1024), 0, stream>>>(ea, (float*)d_out);
}

// Round 9
// 291.126 us; speedup vs baseline: 1.0032x; 1.0032x over previous
//
#include <hip/hip_runtime.h>

// Per-node MLP 16->256->128->6->128->256->1 (tanh...sigmoid) on
// edge_attr.reshape(500000,16). x / edge_index are dead inputs.
//
// R9 = R8 with the launch bound fixed. R8's __launch_bounds__(1024,4) was
// interpreted as min BLOCKS/CU (CUDA semantics): 4x16 waves -> 32-wave clamp
// -> 8 waves/EU -> 64-VGPR budget -> full activation spill (FETCH 160MB,
// WRITE 79MB). (1024,1) -> 16 waves -> 4 waves/EU -> 128-VGPR budget.
// Structure: ONE merged kernel, all weights LDS-resident (156.7KB, 1
// block/CU), z stays in registers; sigma-folded weights (R7); in-lane C->B
// via permuted-k weights (R6); fence windows (R5); split MFMA acc chains (R8).

#define N_NODES 500000

// ---- weight-image layout in g_img == LDS layout (bytes) ----
#define OFF_W1 0        // 16 x 512B  (L1: K=16, standard k-order, x -2log2e)
#define OFF_W2 8192     // 64 x 1KB   (L2, permuted k, x -4log2e)
#define OFF_W3 73728    // 4  x 1KB   (L3, permuted k, x -4log2e)
#define OFF_W4 77824    // 8  x 1KB   (L4: z C-layout feed, x -4log2e)
#define OFF_W5 86016    // 64 x 1KB   (L5, permuted k, x -4log2e)
#define OFF_WO 151552   // 256 f32 (2*Wo)
#define OFF_B1 152576   // 256 f32 (S*b1)
#define OFF_B2 153600   // 128 f32 (S*(be1 - colsum We1))
#define OFF_B3 154112   // 16 f32  (S*(be2 - colsum We2), 6 valid)
#define OFF_B4 154176   // 128 f32 (S*(bd1 - colsum Wd1))
#define OFF_B5 154688   // 256 f32 (S*(bd2 - colsum Wd2))
#define OFF_EXTRA 155712 // 16B: [0] = bo - Sum Wo
#define OFF_ZERO  155728 // 512B zeros (L1 K-pad A rows)
#define IMG_END   156240
#define IMG_ALLOC 156672   // staging tail pad
#define ALL_LDS   156672   // <= 163840: 1 block/CU

#define SCONST (-2.8853900817779268f)   // -2*log2(e)

typedef _Float16 half8  __attribute__((ext_vector_type(8)));
typedef __fp16   pk16x2 __attribute__((ext_vector_type(2)));
typedef float    f32x4  __attribute__((ext_vector_type(4)));
typedef int      int4v  __attribute__((ext_vector_type(4)));

__device__ __align__(16) char g_img[IMG_ALLOC];

static __device__ __forceinline__ unsigned pack_f16_rne(float a, float b) {
  _Float16 ha = (_Float16)a, hb = (_Float16)b;
  unsigned short ua = __builtin_bit_cast(unsigned short, ha);
  unsigned short ub = __builtin_bit_cast(unsigned short, hb);
  return (unsigned)ua | ((unsigned)ub << 16);
}
static __device__ __forceinline__ int pkrtz(float a, float b) {
  pk16x2 h = __builtin_amdgcn_cvt_pkrtz(a, b);
  return __builtin_bit_cast(int, h);
}
// s = 1/(1+2^y); with y = -2*log2e*(Wx+b) this is sigma(2*(Wx+b)).
static __device__ __forceinline__ float sig2(float y) {
  float e = __builtin_amdgcn_exp2f(y);
  return __builtin_amdgcn_rcpf(1.0f + e);
}
static __device__ __forceinline__ float sigmoid_f(float x) {
  float e = __builtin_amdgcn_exp2f(x * -1.4426950408889634f);
  return __builtin_amdgcn_rcpf(1.0f + e);
}
static __device__ __forceinline__ f32x4 mfma16(half8 a, int4v b, f32x4 c) {
  return __builtin_amdgcn_mfma_f32_16x16x32_f16(a, __builtin_bit_cast(half8, b), c, 0, 0, 0);
}
static __device__ __forceinline__ half8 lda(const char* smem, int off) {
  return *(const half8*)(smem + off);
}
static __device__ __forceinline__ f32x4 ldf4(const char* smem, int off) {
  return *(const f32x4*)(smem + off);
}
#define FENCE() __builtin_amdgcn_sched_barrier(0)

struct PK2 { int lo, hi; };
static __device__ __forceinline__ PK2 tp(f32x4 a) {
  PK2 p;
  p.lo = pkrtz(sig2(a.x), sig2(a.y));
  p.hi = pkrtz(sig2(a.z), sig2(a.w));
  return p;
}

// ---------------- prep (unchanged from R7/R8) ----------------
__global__ void gnn_prep(const float* __restrict__ W1,  const float* __restrict__ b1,
                         const float* __restrict__ We1, const float* __restrict__ be1,
                         const float* __restrict__ We2, const float* __restrict__ be2,
                         const float* __restrict__ Wd1, const float* __restrict__ bd1,
                         const float* __restrict__ Wd2, const float* __restrict__ bd2,
                         const float* __restrict__ Wo,  const float* __restrict__ bo)
{
  int t = blockIdx.x * 256 + threadIdx.x;
  int off = t * 4;
  if (off >= IMG_END) return;
  unsigned val;
  if (off < OFF_W2) {                     // L1 (K=16): standard order, S*W1
    int rel = off;
    int mi = rel >> 9, li = (rel >> 4) & 31, j2 = (rel >> 2) & 3;
    int fout = mi * 16 + (li & 15);
    int k0 = (li >> 4) * 8 + j2 * 2;
    val = pack_f16_rne(SCONST * W1[k0 * 256 + fout], SCONST * W1[(k0 + 1) * 256 + fout]);
  } else if (off < OFF_W3) {              // L2: permuted k, 2S*We1
    int rel = off - OFF_W2;
    int blk = rel >> 10, li = (rel >> 4) & 63, j2 = (rel >> 2) & 3;
    int mi = blk >> 3, ki = blk & 7;
    int fout = mi * 16 + (li & 15);
    int k0 = ki * 32 + 4 * (li >> 4) + 16 * (j2 >> 1) + 2 * (j2 & 1);
    val = pack_f16_rne(2.0f * SCONST * We1[k0 * 128 + fout],
                       2.0f * SCONST * We1[(k0 + 1) * 128 + fout]);
  } else if (off < OFF_W4) {              // L3: permuted k, 2S*We2 (fout pad 16)
    int rel = off - OFF_W3;
    int ki = rel >> 10, li = (rel >> 4) & 63, j2 = (rel >> 2) & 3;
    int fo = li & 15;
    int k0 = ki * 32 + 4 * (li >> 4) + 16 * (j2 >> 1) + 2 * (j2 & 1);
    float a = (fo < 6) ? 2.0f * SCONST * We2[k0 * 6 + fo] : 0.0f;
    float b = (fo < 6) ? 2.0f * SCONST * We2[(k0 + 1) * 6 + fo] : 0.0f;
    val = pack_f16_rne(a, b);
  } else if (off < OFF_W5) {              // L4: z C-layout feed, 2S*Wd1
    int rel = off - OFF_W4;
    int mi = rel >> 10, li = (rel >> 4) & 63, j2 = (rel >> 2) & 3;
    int fout = mi * 16 + (li & 15);
    int qa = li >> 4;
    unsigned v = 0;
    if (j2 < 2) {
      int k0 = 4 * qa + 2 * j2;
      float a = (k0 < 6)     ? 2.0f * SCONST * Wd1[k0 * 128 + fout]       : 0.0f;
      float b = (k0 + 1 < 6) ? 2.0f * SCONST * Wd1[(k0 + 1) * 128 + fout] : 0.0f;
      v = pack_f16_rne(a, b);
    }
    val = v;
  } else if (off < OFF_WO) {              // L5: permuted k, 2S*Wd2
    int rel = off - OFF_W5;
    int blk = rel >> 10, li = (rel >> 4) & 63, j2 = (rel >> 2) & 3;
    int mi = blk >> 2, ki = blk & 3;
    int fout = mi * 16 + (li & 15);
    int k0 = ki * 32 + 4 * (li >> 4) + 16 * (j2 >> 1) + 2 * (j2 & 1);
    val = pack_f16_rne(2.0f * SCONST * Wd2[k0 * 256 + fout],
                       2.0f * SCONST * Wd2[(k0 + 1) * 256 + fout]);
  } else if (off < OFF_B1) {              // wo' = 2*Wo
    val = __builtin_bit_cast(unsigned, 2.0f * Wo[(off - OFF_WO) >> 2]);
  } else if (off < OFF_B2) {              // S*b1
    val = __builtin_bit_cast(unsigned, SCONST * b1[(off - OFF_B1) >> 2]);
  } else if (off < OFF_B3) {              // S*(be1 - colsum We1)
    int i = (off - OFF_B2) >> 2;
    float s = 0.0f;
    for (int k = 0; k < 256; ++k) s += We1[k * 128 + i];
    val = __builtin_bit_cast(unsigned, SCONST * (be1[i] - s));
  } else if (off < OFF_B4) {              // S*(be2 - colsum We2), pad 0
    int i = (off - OFF_B3) >> 2;
    float v = 0.0f;
    if (i < 6) {
      float s = 0.0f;
      for (int k = 0; k < 128; ++k) s += We2[k * 6 + i];
      v = SCONST * (be2[i] - s);
    }
    val = __builtin_bit_cast(unsigned, v);
  } else if (off < OFF_B5) {              // S*(bd1 - colsum Wd1)
    int i = (off - OFF_B4) >> 2;
    float s = 0.0f;
    for (int k = 0; k < 6; ++k) s += Wd1[k * 128 + i];
    val = __builtin_bit_cast(unsigned, SCONST * (bd1[i] - s));
  } else if (off < OFF_EXTRA) {           // S*(bd2 - colsum Wd2)
    int i = (off - OFF_B5) >> 2;
    float s = 0.0f;
    for (int k = 0; k < 128; ++k) s += Wd2[k * 256 + i];
    val = __builtin_bit_cast(unsigned, SCONST * (bd2[i] - s));
  } else if (off == OFF_EXTRA) {          // bo' = bo - Sum Wo
    float s = 0.0f;
    for (int k = 0; k < 256; ++k) s += Wo[k];
    val = __builtin_bit_cast(unsigned, bo[0] - s);
  } else {                                // extra slot tail + zero block
    val = 0;
  }
  *(unsigned*)(g_img + off) = val;
}

static __device__ __forceinline__ void stage_chunk(const char* src, char* dst) {
  __builtin_amdgcn_global_load_lds(
      (const __attribute__((address_space(1))) void*)src,
      (__attribute__((address_space(3))) void*)dst, 16, 0, 0);
}

// ================= merged kernel: L1..L5 + output =================

#define L1_PAIR(KO, OUT_G0, OUT_G1) do {                                   \
    half8 Ae = lda(smem, w1b + (2*(KO))*w1s);                              \
    half8 Ao = lda(smem, w1b + (2*(KO)+1)*w1s);                            \
    f32x4 be_ = ldf4(smem, OFF_B1 + (2*(KO))*64 + q*16);                   \
    f32x4 bo_ = ldf4(smem, OFF_B1 + (2*(KO)+1)*64 + q*16);                 \
    f32x4 ae0 = mfma16(Ae, b1g0, be_);                                     \
    f32x4 ae1 = mfma16(Ae, b1g1, be_);                                     \
    f32x4 ao0 = mfma16(Ao, b1g0, bo_);                                     \
    f32x4 ao1 = mfma16(Ao, b1g1, bo_);                                     \
    PK2 pe0 = tp(ae0), po0 = tp(ao0), pe1 = tp(ae1), po1 = tp(ao1);        \
    OUT_G0.x = pe0.lo; OUT_G0.y = pe0.hi; OUT_G0.z = po0.lo; OUT_G0.w = po0.hi; \
    OUT_G1.x = pe1.lo; OUT_G1.y = pe1.hi; OUT_G1.z = po1.lo; OUT_G1.w = po1.hi; \
    FENCE();                                                               \
  } while (0)

// Split accumulator chains: ki 0..3 on the bias-chain, ki 4..7 on a zero
// chain, summed at the end — 2x independent MFMA chains per output.
#define L2_MI(MI, ACC0, ACC1) do {                                                            \
    f32x4 bb = ldf4(smem, OFF_B2 + (MI)*64 + q*16);                                           \
    f32x4 x0a = bb, x0b = zf4, x1a = bb, x1b = zf4;                                           \
    half8 A;                                                                                  \
    A = lda(smem, OFF_W2 + ((MI)*8+0)*1024 + ln*16); x0a = mfma16(A, c2g0_0, x0a); x1a = mfma16(A, c2g1_0, x1a); \
    A = lda(smem, OFF_W2 + ((MI)*8+4)*1024 + ln*16); x0b = mfma16(A, c2g0_4, x0b); x1b = mfma16(A, c2g1_4, x1b); \
    A = lda(smem, OFF_W2 + ((MI)*8+1)*1024 + ln*16); x0a = mfma16(A, c2g0_1, x0a); x1a = mfma16(A, c2g1_1, x1a); \
    A = lda(smem, OFF_W2 + ((MI)*8+5)*1024 + ln*16); x0b = mfma16(A, c2g0_5, x0b); x1b = mfma16(A, c2g1_5, x1b); \
    A = lda(smem, OFF_W2 + ((MI)*8+2)*1024 + ln*16); x0a = mfma16(A, c2g0_2, x0a); x1a = mfma16(A, c2g1_2, x1a); \
    A = lda(smem, OFF_W2 + ((MI)*8+6)*1024 + ln*16); x0b = mfma16(A, c2g0_6, x0b); x1b = mfma16(A, c2g1_6, x1b); \
    A = lda(smem, OFF_W2 + ((MI)*8+3)*1024 + ln*16); x0a = mfma16(A, c2g0_3, x0a); x1a = mfma16(A, c2g1_3, x1a); \
    A = lda(smem, OFF_W2 + ((MI)*8+7)*1024 + ln*16); x0b = mfma16(A, c2g0_7, x0b); x1b = mfma16(A, c2g1_7, x1b); \
    ACC0 = x0a + x0b; ACC1 = x1a + x1b;                                                       \
  } while (0)

#define L2_PAIR(KO, OUT_G0, OUT_G1) do {                                   \
    f32x4 ve0, ve1, vo0, vo1;                                              \
    L2_MI(2*(KO),   ve0, ve1);                                             \
    FENCE();                                                               \
    L2_MI(2*(KO)+1, vo0, vo1);                                             \
    PK2 pe0 = tp(ve0), po0 = tp(vo0), pe1 = tp(ve1), po1 = tp(vo1);        \
    OUT_G0.x = pe0.lo; OUT_G0.y = pe0.hi; OUT_G0.z = po0.lo; OUT_G0.w = po0.hi; \
    OUT_G1.x = pe1.lo; OUT_G1.y = pe1.hi; OUT_G1.z = po1.lo; OUT_G1.w = po1.hi; \
    FENCE();                                                               \
  } while (0)

#define L4_MI(MI, ACC0, ACC1) do {                                         \
    f32x4 bb = ldf4(smem, OFF_B4 + (MI)*64 + q*16);                        \
    half8 A = lda(smem, OFF_W4 + (MI)*1024 + ln*16);                       \
    ACC0 = mfma16(A, b4g0, bb);                                            \
    ACC1 = mfma16(A, b4g1, bb);                                            \
  } while (0)

#define L4_PAIR(KO, OUT_G0, OUT_G1) do {                                   \
    f32x4 ve0, ve1, vo0, vo1;                                              \
    L4_MI(2*(KO),   ve0, ve1);                                             \
    L4_MI(2*(KO)+1, vo0, vo1);                                             \
    PK2 pe0 = tp(ve0), po0 = tp(vo0), pe1 = tp(ve1), po1 = tp(vo1);        \
    OUT_G0.x = pe0.lo; OUT_G0.y = pe0.hi; OUT_G0.z = po0.lo; OUT_G0.w = po0.hi; \
    OUT_G1.x = pe1.lo; OUT_G1.y = pe1.hi; OUT_G1.z = po1.lo; OUT_G1.w = po1.hi; \
    FENCE();                                                               \
  } while (0)

#define L5_MI(MI) do {                                                                        \
    f32x4 bb = ldf4(smem, OFF_B5 + (MI)*64 + q*16);                                           \
    f32x4 x0a = bb, x0b = zf4, x1a = bb, x1b = zf4;                                           \
    half8 A;                                                                                  \
    A = lda(smem, OFF_W5 + ((MI)*4+0)*1024 + ln*16); x0a = mfma16(A, c5g0_0, x0a); x1a = mfma16(A, c5g1_0, x1a); \
    A = lda(smem, OFF_W5 + ((MI)*4+2)*1024 + ln*16); x0b = mfma16(A, c5g0_2, x0b); x1b = mfma16(A, c5g1_2, x1b); \
    A = lda(smem, OFF_W5 + ((MI)*4+1)*1024 + ln*16); x0a = mfma16(A, c5g0_1, x0a); x1a = mfma16(A, c5g1_1, x1a); \
    A = lda(smem, OFF_W5 + ((MI)*4+3)*1024 + ln*16); x0b = mfma16(A, c5g0_3, x0b); x1b = mfma16(A, c5g1_3, x1b); \
    f32x4 a0 = x0a + x0b, a1 = x1a + x1b;                                                     \
    f32x4 wo = ldf4(smem, OFF_WO + (MI)*64 + q*16);                                           \
    part0 += sig2(a0.x)*wo.x + sig2(a0.y)*wo.y + sig2(a0.z)*wo.z + sig2(a0.w)*wo.w;           \
    part1 += sig2(a1.x)*wo.x + sig2(a1.y)*wo.y + sig2(a1.z)*wo.z + sig2(a1.w)*wo.w;           \
    FENCE();                                                                                  \
  } while (0)

__global__ __launch_bounds__(1024, 1)   // 16 waves, 1 block/CU -> 4 waves/EU -> 128-VGPR budget
void gnn_all(const float* __restrict__ ea, float* __restrict__ out)
{
  __shared__ __align__(16) char smem[ALL_LDS];
  const int tid = threadIdx.x;
  const int wv = tid >> 6, ln = tid & 63;   // 16 waves

  // ---- stage whole weight image (LDS mirrors g_img) ----
#pragma unroll 1
  for (int r = 0; r < 10; ++r) {
    int cb = r * 16 + wv;
    if (cb < 153)
      stage_chunk(g_img + (size_t)cb * 1024 + ln * 16,
                  smem + (size_t)cb * 1024 + ln * 16);
  }
  __syncthreads();

  const int q = ln >> 4, c = ln & 15;
  const bool qlo = (q < 2);
  const int lnl16 = (ln & 31) * 16;
  const int w1b = qlo ? (OFF_W1 + lnl16) : (OFF_ZERO + lnl16);
  const int w1s = qlo ? 512 : 0;
  const float bo2 = *(const float*)(smem + OFF_EXTRA);   // bo - Sum Wo
  const f32x4 zf4 = {0.0f, 0.0f, 0.0f, 0.0f};

  const int NT = (N_NODES + 511) / 512;   // 977 tiles of 512 nodes (16 waves)
#pragma unroll 1
  for (int t = blockIdx.x; t < NT; t += gridDim.x) {
    const int base = t * 512 + wv * 32;

    // ---- L1 input: edge_attr as X^T ----
    int nl = base + (q >> 1) * 16 + c;
    if (nl > N_NODES - 1) nl = N_NODES - 1;
    const f32x4* ea4 = (const f32x4*)ea;
    size_t eb = (size_t)nl * 4 + (size_t)((q & 1) * 2);
    f32x4 vlo = ea4[eb];
    f32x4 vhi = ea4[eb + 1];
    int4v b1g0;
    b1g0.x = pkrtz(vlo.x, vlo.y); b1g0.y = pkrtz(vlo.z, vlo.w);
    b1g0.z = pkrtz(vhi.x, vhi.y); b1g0.w = pkrtz(vhi.z, vhi.w);
    int sh = (ln + 32) & 63;
    int4v b1g1;
    b1g1.x = __shfl(b1g0.x, sh, 64); b1g1.y = __shfl(b1g0.y, sh, 64);
    b1g1.z = __shfl(b1g0.z, sh, 64); b1g1.w = __shfl(b1g0.w, sh, 64);

    // ---- L1: 16 -> 256 -> L2 B-frags ----
    int4v c2g0_0, c2g0_1, c2g0_2, c2g0_3, c2g0_4, c2g0_5, c2g0_6, c2g0_7;
    int4v c2g1_0, c2g1_1, c2g1_2, c2g1_3, c2g1_4, c2g1_5, c2g1_6, c2g1_7;
    L1_PAIR(0, c2g0_0, c2g1_0);
    L1_PAIR(1, c2g0_1, c2g1_1);
    L1_PAIR(2, c2g0_2, c2g1_2);
    L1_PAIR(3, c2g0_3, c2g1_3);
    L1_PAIR(4, c2g0_4, c2g1_4);
    L1_PAIR(5, c2g0_5, c2g1_5);
    L1_PAIR(6, c2g0_6, c2g1_6);
    L1_PAIR(7, c2g0_7, c2g1_7);

    // ---- L2: 256 -> 128 -> L3 B-frags ----
    int4v c3g0_0, c3g0_1, c3g0_2, c3g0_3;
    int4v c3g1_0, c3g1_1, c3g1_2, c3g1_3;
    L2_PAIR(0, c3g0_0, c3g1_0);
    L2_PAIR(1, c3g0_1, c3g1_1);
    L2_PAIR(2, c3g0_2, c3g1_2);
    L2_PAIR(3, c3g0_3, c3g1_3);

    // ---- L3: 128 -> 6 (split chains 2+2) ----
    f32x4 bb3 = ldf4(smem, OFF_B3 + q * 16);
    f32x4 z0a = bb3, z0b = zf4, z1a = bb3, z1b = zf4;
    {
      half8 A;
      A = lda(smem, OFF_W3 + 0 * 1024 + ln * 16); z0a = mfma16(A, c3g0_0, z0a); z1a = mfma16(A, c3g1_0, z1a);
      A = lda(smem, OFF_W3 + 2 * 1024 + ln * 16); z0b = mfma16(A, c3g0_2, z0b); z1b = mfma16(A, c3g1_2, z1b);
      A = lda(smem, OFF_W3 + 1 * 1024 + ln * 16); z0a = mfma16(A, c3g0_1, z0a); z1a = mfma16(A, c3g1_1, z1a);
      A = lda(smem, OFF_W3 + 3 * 1024 + ln * 16); z0b = mfma16(A, c3g0_3, z0b); z1b = mfma16(A, c3g1_3, z1b);
    }
    PK2 p3g0 = tp(z0a + z0b);
    PK2 p3g1 = tp(z1a + z1b);
    FENCE();

    // ---- L4 B-frags: direct in-register feed ----
    int4v b4g0, b4g1;
    b4g0.x = p3g0.lo; b4g0.y = p3g0.hi; b4g0.z = 0; b4g0.w = 0;
    b4g1.x = p3g1.lo; b4g1.y = p3g1.hi; b4g1.z = 0; b4g1.w = 0;

    // ---- L4: 6 -> 128 -> L5 B-frags ----
    int4v c5g0_0, c5g0_1, c5g0_2, c5g0_3;
    int4v c5g1_0, c5g1_1, c5g1_2, c5g1_3;
    L4_PAIR(0, c5g0_0, c5g1_0);
    L4_PAIR(1, c5g0_1, c5g1_1);
    L4_PAIR(2, c5g0_2, c5g1_2);
    L4_PAIR(3, c5g0_3, c5g1_3);

    // ---- L5 + output: out = sigma(Sum wo'*s5 + bo') ----
    float part0 = 0.0f, part1 = 0.0f;
    L5_MI(0);  L5_MI(1);  L5_MI(2);  L5_MI(3);
    L5_MI(4);  L5_MI(5);  L5_MI(6);  L5_MI(7);
    L5_MI(8);  L5_MI(9);  L5_MI(10); L5_MI(11);
    L5_MI(12); L5_MI(13); L5_MI(14); L5_MI(15);

    part0 += __shfl_xor(part0, 16, 64); part0 += __shfl_xor(part0, 32, 64);
    part1 += __shfl_xor(part1, 16, 64); part1 += __shfl_xor(part1, 32, 64);
    if (q < 2) {
      int node = base + q * 16 + c;
      if (node < N_NODES) {
        float v = ((q == 0) ? part0 : part1) + bo2;
        out[node] = sigmoid_f(v);
      }
    }
  }
}

extern "C" void kernel_launch(void* const* d_in, const int* in_sizes, int n_in,
                              void* d_out, int out_size, void* d_ws, size_t ws_size,
                              hipStream_t stream) {
  (void)in_sizes; (void)n_in; (void)d_ws; (void)ws_size; (void)out_size;
  const float* ea  = (const float*)d_in[2];
  const float* W1  = (const float*)d_in[3];
  const float* b1  = (const float*)d_in[4];
  const float* We1 = (const float*)d_in[5];
  const float* be1 = (const float*)d_in[6];
  const float* We2 = (const float*)d_in[7];
  const float* be2 = (const float*)d_in[8];
  const float* Wd1 = (const float*)d_in[9];
  const float* bd1 = (const float*)d_in[10];
  const float* Wd2 = (const float*)d_in[11];
  const float* bd2 = (const float*)d_in[12];
  const float* Wo  = (const float*)d_in[13];
  const float* bo  = (const float*)d_in[14];

  gnn_prep<<<dim3((IMG_END / 4 + 255) / 256), dim3(256), 0, stream>>>(
      W1, b1, We1, be1, We2, be2, Wd1, bd1, Wd2, bd2, Wo, bo);
  gnn_all<<<dim3(256), dim3(1024), 0, stream>>>(ea, (float*)d_out);
}

// Round 10
// 243.305 us; speedup vs baseline: 1.2004x; 1.1965x over previous
//
#include <hip/hip_runtime.h>

// Per-node MLP 16->256->128->6->128->256->1 (tanh...sigmoid) on
// edge_attr.reshape(500000,16). x / edge_index are dead inputs.
//
// R10 = R7 split-kernel structure (merged 1024-thread variant is blocked:
// compiler budgets VGPRs for 2 blocks/CU -> 64 VGPRs at 1024 threads,
// observed R8/R9) + three stall reducers:
//  - split MFMA accumulator chains in L2/L3/L5 (2x independent chains/window)
//  - software prefetch of ea (k1) and z (k2) across tiles
//  - L4 bias folded into W4 row 6 vs forced z slot-6 = 1.0 (kills 8 ldf4/tile);
//    L1 fences every 2 pairs.
// Carried: sigma-folded weights (R7), in-lane C->B via permuted-k (R6),
// fence windows vs scheduler hoisting (R5), zero bank conflicts.

#define N_NODES 500000

// ---- weight-image layout in g_img (bytes) ----
#define OFF_W1 0        // 16 x 512B  (L1: K=16, standard k-order, x -2log2e)
#define OFF_W2 8192     // 64 x 1KB   (L2, permuted k, x -4log2e)
#define OFF_W3 73728    // 4  x 1KB   (L3, permuted k, x -4log2e)
#define OFF_W4 77824    // 8  x 1KB   (L4: z C-layout feed, x -4log2e; row6=bias)
#define OFF_W5 86016    // 64 x 1KB   (L5, permuted k, x -4log2e)
#define OFF_WO 151552   // 256 f32 (2*Wo)
#define OFF_B1 152576   // 256 f32 (S*b1)
#define OFF_B2 153600   // 128 f32 (S*(be1 - colsum We1))
#define OFF_B3 154112   // 16 f32  (S*(be2 - colsum We2), 6 valid)
#define OFF_B4 154176   // 128 f32 (unused at runtime now; layout kept)
#define OFF_B5 154688   // 256 f32 (S*(bd2 - colsum Wd2))
#define OFF_EXTRA 155712 // 16B: [0] = bo - Sum Wo
#define OFF_ZERO  155728 // 512B zeros (L1 K-pad A rows)
#define IMG_END   156240
#define IMG_ALLOC 156672

// ---- K1 LDS: [W1 W2 W3][B1 B2 B3][Z] ----
#define K1_B1    77824
#define K1_B2    78848
#define K1_B3    79360
#define K1_Z     79872
#define K1_LDS   80384     // x2 blocks = 160768 <= 163840
// ---- K2 LDS: [W4][W5 WO][B4 B5] ----
#define K2_LDS   76800
#define K2_W4    0
#define K2_W5    8192
#define K2_WO    73728
#define K2_B4    74752
#define K2_B5    75264

#define SCONST (-2.8853900817779268f)   // -2*log2(e)

typedef _Float16 half8  __attribute__((ext_vector_type(8)));
typedef __fp16   pk16x2 __attribute__((ext_vector_type(2)));
typedef float    f32x4  __attribute__((ext_vector_type(4)));
typedef int      int4v  __attribute__((ext_vector_type(4)));

__device__ __align__(16) char g_img[IMG_ALLOC];

static __device__ __forceinline__ unsigned pack_f16_rne(float a, float b) {
  _Float16 ha = (_Float16)a, hb = (_Float16)b;
  unsigned short ua = __builtin_bit_cast(unsigned short, ha);
  unsigned short ub = __builtin_bit_cast(unsigned short, hb);
  return (unsigned)ua | ((unsigned)ub << 16);
}
static __device__ __forceinline__ int pkrtz(float a, float b) {
  pk16x2 h = __builtin_amdgcn_cvt_pkrtz(a, b);
  return __builtin_bit_cast(int, h);
}
// s = 1/(1+2^y); with y = -2*log2e*(Wx+b) this is sigma(2*(Wx+b)).
static __device__ __forceinline__ float sig2(float y) {
  float e = __builtin_amdgcn_exp2f(y);
  return __builtin_amdgcn_rcpf(1.0f + e);
}
static __device__ __forceinline__ float sigmoid_f(float x) {
  float e = __builtin_amdgcn_exp2f(x * -1.4426950408889634f);
  return __builtin_amdgcn_rcpf(1.0f + e);
}
static __device__ __forceinline__ f32x4 mfma16(half8 a, int4v b, f32x4 c) {
  return __builtin_amdgcn_mfma_f32_16x16x32_f16(a, __builtin_bit_cast(half8, b), c, 0, 0, 0);
}
static __device__ __forceinline__ half8 lda(const char* smem, int off) {
  return *(const half8*)(smem + off);
}
static __device__ __forceinline__ f32x4 ldf4(const char* smem, int off) {
  return *(const f32x4*)(smem + off);
}
#define FENCE() __builtin_amdgcn_sched_barrier(0)

struct PK2 { int lo, hi; };
static __device__ __forceinline__ PK2 tp(f32x4 a) {
  PK2 p;
  p.lo = pkrtz(sig2(a.x), sig2(a.y));
  p.hi = pkrtz(sig2(a.z), sig2(a.w));
  return p;
}

// ---------------- prep ----------------
__global__ void gnn_prep(const float* __restrict__ W1,  const float* __restrict__ b1,
                         const float* __restrict__ We1, const float* __restrict__ be1,
                         const float* __restrict__ We2, const float* __restrict__ be2,
                         const float* __restrict__ Wd1, const float* __restrict__ bd1,
                         const float* __restrict__ Wd2, const float* __restrict__ bd2,
                         const float* __restrict__ Wo,  const float* __restrict__ bo)
{
  int t = blockIdx.x * 256 + threadIdx.x;
  int off = t * 4;
  if (off >= IMG_END) return;
  unsigned val;
  if (off < OFF_W2) {                     // L1 (K=16): standard order, S*W1
    int rel = off;
    int mi = rel >> 9, li = (rel >> 4) & 31, j2 = (rel >> 2) & 3;
    int fout = mi * 16 + (li & 15);
    int k0 = (li >> 4) * 8 + j2 * 2;
    val = pack_f16_rne(SCONST * W1[k0 * 256 + fout], SCONST * W1[(k0 + 1) * 256 + fout]);
  } else if (off < OFF_W3) {              // L2: permuted k, 2S*We1
    int rel = off - OFF_W2;
    int blk = rel >> 10, li = (rel >> 4) & 63, j2 = (rel >> 2) & 3;
    int mi = blk >> 3, ki = blk & 7;
    int fout = mi * 16 + (li & 15);
    int k0 = ki * 32 + 4 * (li >> 4) + 16 * (j2 >> 1) + 2 * (j2 & 1);
    val = pack_f16_rne(2.0f * SCONST * We1[k0 * 128 + fout],
                       2.0f * SCONST * We1[(k0 + 1) * 128 + fout]);
  } else if (off < OFF_W4) {              // L3: permuted k, 2S*We2 (fout pad 16)
    int rel = off - OFF_W3;
    int ki = rel >> 10, li = (rel >> 4) & 63, j2 = (rel >> 2) & 3;
    int fo = li & 15;
    int k0 = ki * 32 + 4 * (li >> 4) + 16 * (j2 >> 1) + 2 * (j2 & 1);
    float a = (fo < 6) ? 2.0f * SCONST * We2[k0 * 6 + fo] : 0.0f;
    float b = (fo < 6) ? 2.0f * SCONST * We2[(k0 + 1) * 6 + fo] : 0.0f;
    val = pack_f16_rne(a, b);
  } else if (off < OFF_W5) {              // L4: z C-layout feed, 2S*Wd1; row6 = bias
    int rel = off - OFF_W4;
    int mi = rel >> 10, li = (rel >> 4) & 63, j2 = (rel >> 2) & 3;
    int fout = mi * 16 + (li & 15);
    int qa = li >> 4;
    unsigned v = 0;
    if (j2 < 2) {
      int k0 = 4 * qa + 2 * j2;
      float a, b;
      if (k0 < 6) {
        a = 2.0f * SCONST * Wd1[k0 * 128 + fout];
        b = (k0 + 1 < 6) ? 2.0f * SCONST * Wd1[(k0 + 1) * 128 + fout] : 0.0f;
      } else if (k0 == 6) {               // bias row: meets forced z slot-6 = 1.0
        float s = 0.0f;
        for (int k = 0; k < 6; ++k) s += Wd1[k * 128 + fout];
        a = SCONST * (bd1[fout] - s);
        b = 0.0f;
      } else { a = 0.0f; b = 0.0f; }
      v = pack_f16_rne(a, b);
    }
    val = v;
  } else if (off < OFF_WO) {              // L5: permuted k, 2S*Wd2
    int rel = off - OFF_W5;
    int blk = rel >> 10, li = (rel >> 4) & 63, j2 = (rel >> 2) & 3;
    int mi = blk >> 2, ki = blk & 3;
    int fout = mi * 16 + (li & 15);
    int k0 = ki * 32 + 4 * (li >> 4) + 16 * (j2 >> 1) + 2 * (j2 & 1);
    val = pack_f16_rne(2.0f * SCONST * Wd2[k0 * 256 + fout],
                       2.0f * SCONST * Wd2[(k0 + 1) * 256 + fout]);
  } else if (off < OFF_B1) {              // wo' = 2*Wo
    val = __builtin_bit_cast(unsigned, 2.0f * Wo[(off - OFF_WO) >> 2]);
  } else if (off < OFF_B2) {              // S*b1
    val = __builtin_bit_cast(unsigned, SCONST * b1[(off - OFF_B1) >> 2]);
  } else if (off < OFF_B3) {              // S*(be1 - colsum We1)
    int i = (off - OFF_B2) >> 2;
    float s = 0.0f;
    for (int k = 0; k < 256; ++k) s += We1[k * 128 + i];
    val = __builtin_bit_cast(unsigned, SCONST * (be1[i] - s));
  } else if (off < OFF_B4) {              // S*(be2 - colsum We2), pad 0
    int i = (off - OFF_B3) >> 2;
    float v = 0.0f;
    if (i < 6) {
      float s = 0.0f;
      for (int k = 0; k < 128; ++k) s += We2[k * 6 + i];
      v = SCONST * (be2[i] - s);
    }
    val = __builtin_bit_cast(unsigned, v);
  } else if (off < OFF_B5) {              // (legacy B4 slot; unused at runtime)
    int i = (off - OFF_B4) >> 2;
    float s = 0.0f;
    for (int k = 0; k < 6; ++k) s += Wd1[k * 128 + i];
    val = __builtin_bit_cast(unsigned, SCONST * (bd1[i] - s));
  } else if (off < OFF_EXTRA) {           // S*(bd2 - colsum Wd2)
    int i = (off - OFF_B5) >> 2;
    float s = 0.0f;
    for (int k = 0; k < 128; ++k) s += Wd2[k * 256 + i];
    val = __builtin_bit_cast(unsigned, SCONST * (bd2[i] - s));
  } else if (off == OFF_EXTRA) {          // bo' = bo - Sum Wo
    float s = 0.0f;
    for (int k = 0; k < 256; ++k) s += Wo[k];
    val = __builtin_bit_cast(unsigned, bo[0] - s);
  } else {                                // extra tail + zero block
    val = 0;
  }
  *(unsigned*)(g_img + off) = val;
}

static __device__ __forceinline__ void stage_chunk(const char* src, char* dst) {
  __builtin_amdgcn_global_load_lds(
      (const __attribute__((address_space(1))) void*)src,
      (__attribute__((address_space(3))) void*)dst, 16, 0, 0);
}

// ================= K1: L1 -> L2 -> L3, z to d_ws =================
#define L1_PAIR(KO, OUT_G0, OUT_G1) do {                                   \
    half8 Ae = lda(smem, w1b + (2*(KO))*w1s);                              \
    half8 Ao = lda(smem, w1b + (2*(KO)+1)*w1s);                            \
    f32x4 be_ = ldf4(smem, K1_B1 + (2*(KO))*64 + q*16);                    \
    f32x4 bo_ = ldf4(smem, K1_B1 + (2*(KO)+1)*64 + q*16);                  \
    f32x4 ae0 = mfma16(Ae, b1g0, be_);                                     \
    f32x4 ae1 = mfma16(Ae, b1g1, be_);                                     \
    f32x4 ao0 = mfma16(Ao, b1g0, bo_);                                     \
    f32x4 ao1 = mfma16(Ao, b1g1, bo_);                                     \
    PK2 pe0 = tp(ae0), po0 = tp(ao0), pe1 = tp(ae1), po1 = tp(ao1);        \
    OUT_G0.x = pe0.lo; OUT_G0.y = pe0.hi; OUT_G0.z = po0.lo; OUT_G0.w = po0.hi; \
    OUT_G1.x = pe1.lo; OUT_G1.y = pe1.hi; OUT_G1.z = po1.lo; OUT_G1.w = po1.hi; \
  } while (0)

// Split accumulator chains: ki 0..3 on the bias-chain, ki 4..7 on a zero
// chain — 2x independent MFMA chains per output.
#define L2_MI(MI, ACC0, ACC1) do {                                                            \
    f32x4 bb = ldf4(smem, K1_B2 + (MI)*64 + q*16);                                            \
    f32x4 x0a = bb, x0b = zf4, x1a = bb, x1b = zf4;                                           \
    half8 A;                                                                                  \
    A = lda(smem, OFF_W2 + ((MI)*8+0)*1024 + ln*16); x0a = mfma16(A, c2g0_0, x0a); x1a = mfma16(A, c2g1_0, x1a); \
    A = lda(smem, OFF_W2 + ((MI)*8+4)*1024 + ln*16); x0b = mfma16(A, c2g0_4, x0b); x1b = mfma16(A, c2g1_4, x1b); \
    A = lda(smem, OFF_W2 + ((MI)*8+1)*1024 + ln*16); x0a = mfma16(A, c2g0_1, x0a); x1a = mfma16(A, c2g1_1, x1a); \
    A = lda(smem, OFF_W2 + ((MI)*8+5)*1024 + ln*16); x0b = mfma16(A, c2g0_5, x0b); x1b = mfma16(A, c2g1_5, x1b); \
    A = lda(smem, OFF_W2 + ((MI)*8+2)*1024 + ln*16); x0a = mfma16(A, c2g0_2, x0a); x1a = mfma16(A, c2g1_2, x1a); \
    A = lda(smem, OFF_W2 + ((MI)*8+6)*1024 + ln*16); x0b = mfma16(A, c2g0_6, x0b); x1b = mfma16(A, c2g1_6, x1b); \
    A = lda(smem, OFF_W2 + ((MI)*8+3)*1024 + ln*16); x0a = mfma16(A, c2g0_3, x0a); x1a = mfma16(A, c2g1_3, x1a); \
    A = lda(smem, OFF_W2 + ((MI)*8+7)*1024 + ln*16); x0b = mfma16(A, c2g0_7, x0b); x1b = mfma16(A, c2g1_7, x1b); \
    ACC0 = x0a + x0b; ACC1 = x1a + x1b;                                                       \
  } while (0)

#define L2_PAIR(KO, OUT_G0, OUT_G1) do {                                   \
    f32x4 ve0, ve1, vo0, vo1;                                              \
    L2_MI(2*(KO),   ve0, ve1);                                             \
    FENCE();                                                               \
    L2_MI(2*(KO)+1, vo0, vo1);                                             \
    PK2 pe0 = tp(ve0), po0 = tp(vo0), pe1 = tp(ve1), po1 = tp(vo1);        \
    OUT_G0.x = pe0.lo; OUT_G0.y = pe0.hi; OUT_G0.z = po0.lo; OUT_G0.w = po0.hi; \
    OUT_G1.x = pe1.lo; OUT_G1.y = pe1.hi; OUT_G1.z = po1.lo; OUT_G1.w = po1.hi; \
    FENCE();                                                               \
  } while (0)

__global__ __launch_bounds__(512)
void gnn_k1(const float* __restrict__ ea, int4v* __restrict__ zbuf)
{
  __shared__ __align__(16) char smem[K1_LDS];
  const int tid = threadIdx.x;
  const int wv = tid >> 6, ln = tid & 63;

#pragma unroll 1
  for (int r = 0; r < 10; ++r) {
    int cb = (r * 8 + wv) << 6;
    if (cb < 5024) {
      int src;
      if (cb < 4864)      src = cb * 16;
      else if (cb < 4992) src = OFF_B1 + (cb - 4864) * 16;
      else                src = OFF_ZERO + (cb - 4992) * 16;
      stage_chunk(g_img + src + ln * 16, smem + (size_t)cb * 16 + ln * 16);
    }
  }
  __syncthreads();

  const int q = ln >> 4, c = ln & 15;
  const bool qlo = (q < 2);
  const int lnl16 = (ln & 31) * 16;
  const int w1b = qlo ? (OFF_W1 + lnl16) : (K1_Z + lnl16);
  const int w1s = qlo ? 512 : 0;
  const int4v zi4 = {0, 0, 0, 0};
  const half8 h8z = __builtin_bit_cast(half8, zi4);
  (void)h8z;
  const f32x4 zf4 = {0.0f, 0.0f, 0.0f, 0.0f};

  const f32x4* ea4 = (const f32x4*)ea;
  const int NT = (N_NODES + 255) / 256;

  // ---- prefetch tile 0's input ----
  int nl0 = blockIdx.x * 256 + wv * 32 + (q >> 1) * 16 + c;
  if (nl0 > N_NODES - 1) nl0 = N_NODES - 1;
  size_t eb0 = (size_t)nl0 * 4 + (size_t)((q & 1) * 2);
  f32x4 vlo = ea4[eb0];
  f32x4 vhi = ea4[eb0 + 1];

#pragma unroll 1
  for (int t = blockIdx.x; t < NT; t += gridDim.x) {
    const int base = t * 256 + wv * 32;

    // ---- consume prefetched input ----
    int4v b1g0;
    b1g0.x = pkrtz(vlo.x, vlo.y); b1g0.y = pkrtz(vlo.z, vlo.w);
    b1g0.z = pkrtz(vhi.x, vhi.y); b1g0.w = pkrtz(vhi.z, vhi.w);
    int sh = (ln + 32) & 63;
    int4v b1g1;
    b1g1.x = __shfl(b1g0.x, sh, 64); b1g1.y = __shfl(b1g0.y, sh, 64);
    b1g1.z = __shfl(b1g0.z, sh, 64); b1g1.w = __shfl(b1g0.w, sh, 64);

    // ---- prefetch next tile's input (fences below keep it early) ----
    int nl2 = (t + gridDim.x) * 256 + wv * 32 + (q >> 1) * 16 + c;
    if (nl2 > N_NODES - 1) nl2 = N_NODES - 1;
    size_t eb2 = (size_t)nl2 * 4 + (size_t)((q & 1) * 2);
    f32x4 nlo = ea4[eb2];
    f32x4 nhi = ea4[eb2 + 1];

    // ---- L1: 16 -> 256 -> L2 B-frags (fence every 2 pairs) ----
    int4v c2g0_0, c2g0_1, c2g0_2, c2g0_3, c2g0_4, c2g0_5, c2g0_6, c2g0_7;
    int4v c2g1_0, c2g1_1, c2g1_2, c2g1_3, c2g1_4, c2g1_5, c2g1_6, c2g1_7;
    L1_PAIR(0, c2g0_0, c2g1_0);
    L1_PAIR(1, c2g0_1, c2g1_1);
    FENCE();
    L1_PAIR(2, c2g0_2, c2g1_2);
    L1_PAIR(3, c2g0_3, c2g1_3);
    FENCE();
    L1_PAIR(4, c2g0_4, c2g1_4);
    L1_PAIR(5, c2g0_5, c2g1_5);
    FENCE();
    L1_PAIR(6, c2g0_6, c2g1_6);
    L1_PAIR(7, c2g0_7, c2g1_7);
    FENCE();

    // ---- L2: 256 -> 128 -> L3 B-frags ----
    int4v c3g0_0, c3g0_1, c3g0_2, c3g0_3;
    int4v c3g1_0, c3g1_1, c3g1_2, c3g1_3;
    L2_PAIR(0, c3g0_0, c3g1_0);
    L2_PAIR(1, c3g0_1, c3g1_1);
    L2_PAIR(2, c3g0_2, c3g1_2);
    L2_PAIR(3, c3g0_3, c3g1_3);

    // ---- L3: 128 -> 6 (split chains 2+2) ----
    f32x4 bb3 = ldf4(smem, K1_B3 + q * 16);
    f32x4 z0a = bb3, z0b = zf4, z1a = bb3, z1b = zf4;
    {
      half8 A;
      A = lda(smem, OFF_W3 + 0 * 1024 + ln * 16); z0a = mfma16(A, c3g0_0, z0a); z1a = mfma16(A, c3g1_0, z1a);
      A = lda(smem, OFF_W3 + 2 * 1024 + ln * 16); z0b = mfma16(A, c3g0_2, z0b); z1b = mfma16(A, c3g1_2, z1b);
      A = lda(smem, OFF_W3 + 1 * 1024 + ln * 16); z0a = mfma16(A, c3g0_1, z0a); z1a = mfma16(A, c3g1_1, z1a);
      A = lda(smem, OFF_W3 + 3 * 1024 + ln * 16); z0b = mfma16(A, c3g0_3, z0b); z1b = mfma16(A, c3g1_3, z1b);
    }
    PK2 p3g0 = tp(z0a + z0b);
    PK2 p3g1 = tp(z1a + z1b);

    // ---- store z (sigma) C-layout; force slot 6 (both groups) to f16 1.0
    //      so W4's bias row multiplies by exactly 1 in K2 ----
    if (ln < 32) {
      int4v zv;
      zv.x = p3g0.lo; zv.y = p3g0.hi; zv.z = p3g1.lo; zv.w = p3g1.hi;
      if (q == 1) {
        zv.y = (zv.y & 0xFFFF0000) | 0x3C00;   // group-0 row 6 = 1.0
        zv.w = (zv.w & 0xFFFF0000) | 0x3C00;   // group-1 row 6 = 1.0
      }
      zbuf[(size_t)(t * 8 + wv) * 32 + ln] = zv;
    }

    vlo = nlo; vhi = nhi;
  }
}

// ================= K2: L4 -> L5 -> out =================
// L4 bias rides W4 row 6 x z slot-6 (=1.0): C init is zero, no B4 loads.
#define L4_MI(MI, ACC0, ACC1) do {                                         \
    half8 A = lda(smem, K2_W4 + (MI)*1024 + ln*16);                        \
    ACC0 = mfma16(A, b4g0, zf4);                                           \
    ACC1 = mfma16(A, b4g1, zf4);                                           \
  } while (0)

#define L4_PAIR(KO, OUT_G0, OUT_G1) do {                                   \
    f32x4 ve0, ve1, vo0, vo1;                                              \
    L4_MI(2*(KO),   ve0, ve1);                                             \
    L4_MI(2*(KO)+1, vo0, vo1);                                             \
    PK2 pe0 = tp(ve0), po0 = tp(vo0), pe1 = tp(ve1), po1 = tp(vo1);        \
    OUT_G0.x = pe0.lo; OUT_G0.y = pe0.hi; OUT_G0.z = po0.lo; OUT_G0.w = po0.hi; \
    OUT_G1.x = pe1.lo; OUT_G1.y = pe1.hi; OUT_G1.z = po1.lo; OUT_G1.w = po1.hi; \
    FENCE();                                                               \
  } while (0)

#define L5_MI(MI) do {                                                                        \
    f32x4 bb = ldf4(smem, K2_B5 + (MI)*64 + q*16);                                            \
    f32x4 x0a = bb, x0b = zf4, x1a = bb, x1b = zf4;                                           \
    half8 A;                                                                                  \
    A = lda(smem, K2_W5 + ((MI)*4+0)*1024 + ln*16); x0a = mfma16(A, c5g0_0, x0a); x1a = mfma16(A, c5g1_0, x1a); \
    A = lda(smem, K2_W5 + ((MI)*4+2)*1024 + ln*16); x0b = mfma16(A, c5g0_2, x0b); x1b = mfma16(A, c5g1_2, x1b); \
    A = lda(smem, K2_W5 + ((MI)*4+1)*1024 + ln*16); x0a = mfma16(A, c5g0_1, x0a); x1a = mfma16(A, c5g1_1, x1a); \
    A = lda(smem, K2_W5 + ((MI)*4+3)*1024 + ln*16); x0b = mfma16(A, c5g0_3, x0b); x1b = mfma16(A, c5g1_3, x1b); \
    f32x4 a0 = x0a + x0b, a1 = x1a + x1b;                                                     \
    f32x4 wo = ldf4(smem, K2_WO + (MI)*64 + q*16);                                            \
    part0 += sig2(a0.x)*wo.x + sig2(a0.y)*wo.y + sig2(a0.z)*wo.z + sig2(a0.w)*wo.w;           \
    part1 += sig2(a1.x)*wo.x + sig2(a1.y)*wo.y + sig2(a1.z)*wo.z + sig2(a1.w)*wo.w;           \
    FENCE();                                                                                  \
  } while (0)

__global__ __launch_bounds__(512)
void gnn_k2(const int4v* __restrict__ zbuf, float* __restrict__ out)
{
  __shared__ __align__(16) char smem[K2_LDS];
  const int tid = threadIdx.x;
  const int wv = tid >> 6, ln = tid & 63;

#pragma unroll 1
  for (int r = 0; r < 10; ++r) {
    int cb = (r * 8 + wv) << 6;
    if (cb < 4800) {
      int src;
      if (cb < 512)       src = OFF_W4 + cb * 16;
      else if (cb < 4672) src = OFF_W5 + (cb - 512) * 16;   // W5+WO contiguous
      else                src = OFF_B4 + (cb - 4672) * 16;
      stage_chunk(g_img + src + ln * 16, smem + (size_t)cb * 16 + ln * 16);
    }
  }
  __syncthreads();

  const int q = ln >> 4, c = ln & 15;
  const float bo2 = *(const float*)(g_img + OFF_EXTRA);   // bo - Sum Wo
  const f32x4 zf4 = {0.0f, 0.0f, 0.0f, 0.0f};

  const int NT = (N_NODES + 255) / 256;

  // ---- prefetch tile 0's z ----
  int4v zv = {0, 0, 0, 0};
  if (ln < 32) zv = zbuf[(size_t)(blockIdx.x * 8 + wv) * 32 + ln];

#pragma unroll 1
  for (int t = blockIdx.x; t < NT; t += gridDim.x) {
    const int base = t * 256 + wv * 32;

    // ---- L4 B-frags from prefetched z ----
    int4v b4g0, b4g1;
    b4g0.x = zv.x; b4g0.y = zv.y; b4g0.z = 0; b4g0.w = 0;
    b4g1.x = zv.z; b4g1.y = zv.w; b4g1.z = 0; b4g1.w = 0;

    // ---- prefetch next tile's z ----
    int4v zvn = {0, 0, 0, 0};
    {
      int t2 = t + gridDim.x;
      if (t2 >= NT) t2 = t;           // harmless re-read on last iteration
      if (ln < 32) zvn = zbuf[(size_t)(t2 * 8 + wv) * 32 + ln];
    }

    // ---- L4: 6 -> 128 -> L5 B-frags ----
    int4v c5g0_0, c5g0_1, c5g0_2, c5g0_3;
    int4v c5g1_0, c5g1_1, c5g1_2, c5g1_3;
    L4_PAIR(0, c5g0_0, c5g1_0);
    L4_PAIR(1, c5g0_1, c5g1_1);
    L4_PAIR(2, c5g0_2, c5g1_2);
    L4_PAIR(3, c5g0_3, c5g1_3);

    // ---- L5 + output: out = sigma(Sum wo'*s5 + bo') ----
    float part0 = 0.0f, part1 = 0.0f;
    L5_MI(0);  L5_MI(1);  L5_MI(2);  L5_MI(3);
    L5_MI(4);  L5_MI(5);  L5_MI(6);  L5_MI(7);
    L5_MI(8);  L5_MI(9);  L5_MI(10); L5_MI(11);
    L5_MI(12); L5_MI(13); L5_MI(14); L5_MI(15);

    part0 += __shfl_xor(part0, 16, 64); part0 += __shfl_xor(part0, 32, 64);
    part1 += __shfl_xor(part1, 16, 64); part1 += __shfl_xor(part1, 32, 64);
    if (q < 2) {
      int node = base + q * 16 + c;
      if (node < N_NODES) {
        float v = ((q == 0) ? part0 : part1) + bo2;
        out[node] = sigmoid_f(v);
      }
    }

    zv = zvn;
  }
}

extern "C" void kernel_launch(void* const* d_in, const int* in_sizes, int n_in,
                              void* d_out, int out_size, void* d_ws, size_t ws_size,
                              hipStream_t stream) {
  (void)in_sizes; (void)n_in; (void)ws_size; (void)out_size;
  const float* ea  = (const float*)d_in[2];
  const float* W1  = (const float*)d_in[3];
  const float* b1  = (const float*)d_in[4];
  const float* We1 = (const float*)d_in[5];
  const float* be1 = (const float*)d_in[6];
  const float* We2 = (const float*)d_in[7];
  const float* be2 = (const float*)d_in[8];
  const float* Wd1 = (const float*)d_in[9];
  const float* bd1 = (const float*)d_in[10];
  const float* Wd2 = (const float*)d_in[11];
  const float* bd2 = (const float*)d_in[12];
  const float* Wo  = (const float*)d_in[13];
  const float* bo  = (const float*)d_in[14];

  gnn_prep<<<dim3((IMG_END / 4 + 255) / 256), dim3(256), 0, stream>>>(
      W1, b1, We1, be1, We2, be2, Wd1, bd1, Wd2, bd2, Wo, bo);
  gnn_k1<<<dim3(512), dim3(512), 0, stream>>>(ea, (int4v*)d_ws);
  gnn_k2<<<dim3(512), dim3(512), 0, stream>>>((const int4v*)d_ws, (float*)d_out);
}